// Round 1
// baseline (790.607 us; speedup 1.0000x reference)
//
#include <hip/hip_runtime.h>
#include <hip/hip_fp16.h>
#include <math.h>

#define B_ 2
#define H_ 16
#define L_ 2048
#define D_ 64
#define SCALE 0.125f
#define OUT_ELEMS ((size_t)B_ * H_ * L_ * D_)

typedef _Float16 half8 __attribute__((ext_vector_type(8)));
typedef float f32x4 __attribute__((ext_vector_type(4)));

// One block = 256 threads = 4 waves. Each block owns (b, h, 64 q-rows).
// Wave w owns q-rows [w*16, w*16+16).
// Pass A: online (m,l) stats via QK^T MFMA. Pass B: recompute QK^T, write
// normalized P to score output, accumulate O += P*V via MFMA.
__global__ __launch_bounds__(256) void attn_kernel(
    const float* __restrict__ Q, const float* __restrict__ K,
    const float* __restrict__ V, const int* __restrict__ M,
    float* __restrict__ out, float* __restrict__ score)
{
  const int qt = blockIdx.x, h = blockIdx.y, b = blockIdx.z;
  const int bh = b * H_ + h;
  const int q0 = qt * 64;
  const int tid = threadIdx.x;
  const int wv = tid >> 6, lane = tid & 63;
  const int lr = lane & 15, lg = lane >> 4;

  // LDS: padded to 72 halves/row (144 B = 16B-aligned stride, conflict-light)
  __shared__ _Float16 Klds[64][72];            // K-chunk [k][d]
  __shared__ _Float16 Vtlds[64][72];           // V-chunk transposed [d][k]
  __shared__ _Float16 Plds[4][16][72];         // per-wave P [qrow][k]
  __shared__ unsigned long long maskbits[64][32]; // 64 q-rows x 2048 k bits

  const float* qb = Q + (size_t)(bh * L_ + q0) * D_;
  const float* kb = K + (size_t)bh * L_ * D_;
  const float* vb = V + (size_t)bh * L_ * D_;
  const int*   mb = M + (size_t)b * L_ * L_ + (size_t)q0 * L_;
  float* ob = out + (size_t)(bh * L_ + q0) * D_;
  float* sb = score + (size_t)(bh * L_ + q0) * L_;

  // ---------- mask bitpack: one __ballot per 64 consecutive k ----------
  for (int w = wv; w < 64 * 32; w += 4) {
    int row = w >> 5, wi = w & 31;
    int val = mb[row * L_ + wi * 64 + lane];
    unsigned long long bits = __ballot(val != 0);
    if (lane == 0) maskbits[row][wi] = bits;
  }

  // ---------- Q fragments (per-lane, fp16), row = wv*16 + lr ----------
  half8 qf[2];
  {
    const float* qr = qb + (size_t)(wv * 16 + lr) * D_;
#pragma unroll
    for (int f = 0; f < 2; ++f) {
      float4 x = *(const float4*)(qr + f * 32 + lg * 8);
      float4 y = *(const float4*)(qr + f * 32 + lg * 8 + 4);
      qf[f] = half8{(_Float16)x.x, (_Float16)x.y, (_Float16)x.z, (_Float16)x.w,
                    (_Float16)y.x, (_Float16)y.y, (_Float16)y.z, (_Float16)y.w};
    }
  }

  const int srow = tid >> 2, sd0 = (tid & 3) * 16;

  auto stageK = [&](int kc) {
    const float* src = kb + (size_t)(kc + srow) * D_ + sd0;
    float4 a = ((const float4*)src)[0];
    float4 c = ((const float4*)src)[1];
    float4 d = ((const float4*)src)[2];
    float4 e = ((const float4*)src)[3];
    float vals[16] = {a.x, a.y, a.z, a.w, c.x, c.y, c.z, c.w,
                      d.x, d.y, d.z, d.w, e.x, e.y, e.z, e.w};
    union { _Float16 hx[16]; uint4 u[2]; } pk;
#pragma unroll
    for (int j = 0; j < 16; ++j) pk.hx[j] = (_Float16)vals[j];
    *(uint4*)&Klds[srow][sd0] = pk.u[0];
    *(uint4*)&Klds[srow][sd0 + 8] = pk.u[1];
  };

  auto stageV = [&](int kc) {
    const float* src = vb + (size_t)(kc + srow) * D_ + sd0;
    float4 a = ((const float4*)src)[0];
    float4 c = ((const float4*)src)[1];
    float4 d = ((const float4*)src)[2];
    float4 e = ((const float4*)src)[3];
    float vals[16] = {a.x, a.y, a.z, a.w, c.x, c.y, c.z, c.w,
                      d.x, d.y, d.z, d.w, e.x, e.y, e.z, e.w};
#pragma unroll
    for (int j = 0; j < 16; ++j) Vtlds[sd0 + j][srow] = (_Float16)vals[j];
  };

  float m_r[4], l_r[4];
#pragma unroll
  for (int r = 0; r < 4; ++r) { m_r[r] = -INFINITY; l_r[r] = 0.f; }

  // ================= pass A: row max / sum statistics =================
  for (int kc = 0; kc < L_; kc += 64) {
    __syncthreads();
    stageK(kc);
    __syncthreads();

    f32x4 acc[4] = {f32x4{0,0,0,0}, f32x4{0,0,0,0}, f32x4{0,0,0,0}, f32x4{0,0,0,0}};
#pragma unroll
    for (int kb4 = 0; kb4 < 4; ++kb4) {
      half8 b0 = *(const half8*)&Klds[kb4 * 16 + lr][lg * 8];
      half8 b1 = *(const half8*)&Klds[kb4 * 16 + lr][32 + lg * 8];
      acc[kb4] = __builtin_amdgcn_mfma_f32_16x16x32_f16(qf[0], b0, acc[kb4], 0, 0, 0);
      acc[kb4] = __builtin_amdgcn_mfma_f32_16x16x32_f16(qf[1], b1, acc[kb4], 0, 0, 0);
    }

    const int wi = kc >> 6;
#pragma unroll
    for (int r = 0; r < 4; ++r) {
      unsigned long long mw = maskbits[wv * 16 + lg * 4 + r][wi];
      float sv[4];
      float cm = -INFINITY;
#pragma unroll
      for (int kb4 = 0; kb4 < 4; ++kb4) {
        bool on = (mw >> (kb4 * 16 + lr)) & 1ull;
        float s = acc[kb4][r] * SCALE;
        sv[kb4] = on ? s : -INFINITY;
        cm = fmaxf(cm, sv[kb4]);
      }
#pragma unroll
      for (int st = 1; st < 16; st <<= 1) cm = fmaxf(cm, __shfl_xor(cm, st));
      float mn = fmaxf(m_r[r], cm);
      float cs = 0.f;
#pragma unroll
      for (int kb4 = 0; kb4 < 4; ++kb4)
        cs += (sv[kb4] > -INFINITY) ? __expf(sv[kb4] - mn) : 0.f;
#pragma unroll
      for (int st = 1; st < 16; st <<= 1) cs += __shfl_xor(cs, st);
      float sc_old = (m_r[r] == mn) ? 1.f : __expf(m_r[r] - mn);
      l_r[r] = l_r[r] * sc_old + cs;
      m_r[r] = mn;
    }
  }

  float inv_l[4], m_use[4];
#pragma unroll
  for (int r = 0; r < 4; ++r) {
    bool ok = l_r[r] > 0.f;
    inv_l[r] = ok ? 1.f / l_r[r] : 0.f;
    m_use[r] = ok ? m_r[r] : 0.f;
  }

  // ================= pass B: write P, accumulate O = P*V =================
  f32x4 o_acc[4] = {f32x4{0,0,0,0}, f32x4{0,0,0,0}, f32x4{0,0,0,0}, f32x4{0,0,0,0}};

  for (int kc = 0; kc < L_; kc += 64) {
    __syncthreads();
    stageK(kc);
    stageV(kc);
    __syncthreads();

    f32x4 acc[4] = {f32x4{0,0,0,0}, f32x4{0,0,0,0}, f32x4{0,0,0,0}, f32x4{0,0,0,0}};
#pragma unroll
    for (int kb4 = 0; kb4 < 4; ++kb4) {
      half8 b0 = *(const half8*)&Klds[kb4 * 16 + lr][lg * 8];
      half8 b1 = *(const half8*)&Klds[kb4 * 16 + lr][32 + lg * 8];
      acc[kb4] = __builtin_amdgcn_mfma_f32_16x16x32_f16(qf[0], b0, acc[kb4], 0, 0, 0);
      acc[kb4] = __builtin_amdgcn_mfma_f32_16x16x32_f16(qf[1], b1, acc[kb4], 0, 0, 0);
    }

    const int wi = kc >> 6;
#pragma unroll
    for (int r = 0; r < 4; ++r) {
      unsigned long long mw = maskbits[wv * 16 + lg * 4 + r][wi];
      float* srow_p = sb + (size_t)(wv * 16 + lg * 4 + r) * L_ + kc;
#pragma unroll
      for (int kb4 = 0; kb4 < 4; ++kb4) {
        bool on = (mw >> (kb4 * 16 + lr)) & 1ull;
        float s = acc[kb4][r] * SCALE;
        float p = on ? __expf(s - m_use[r]) * inv_l[r] : 0.f;
        srow_p[kb4 * 16 + lr] = p;
        Plds[wv][lg * 4 + r][kb4 * 16 + lr] = (_Float16)p;
      }
    }

    // PV: A = P (LDS round-trip), B = V^T (LDS). Same-wave LDS RAW — compiler
    // inserts lgkmcnt waits (no cross-wave sharing of Plds).
#pragma unroll
    for (int ks = 0; ks < 2; ++ks) {
      half8 pa = *(const half8*)&Plds[wv][lr][ks * 32 + lg * 8];
#pragma unroll
      for (int db = 0; db < 4; ++db) {
        half8 vf = *(const half8*)&Vtlds[db * 16 + lr][ks * 32 + lg * 8];
        o_acc[db] = __builtin_amdgcn_mfma_f32_16x16x32_f16(pa, vf, o_acc[db], 0, 0, 0);
      }
    }
  }

  // ---------- write O ----------
#pragma unroll
  for (int db = 0; db < 4; ++db)
#pragma unroll
    for (int r = 0; r < 4; ++r)
      ob[(size_t)(wv * 16 + lg * 4 + r) * D_ + db * 16 + lr] = o_acc[db][r];
}

extern "C" void kernel_launch(void* const* d_in, const int* in_sizes, int n_in,
                              void* d_out, int out_size, void* d_ws, size_t ws_size,
                              hipStream_t stream) {
  const float* q = (const float*)d_in[0];
  const float* k = (const float*)d_in[1];
  const float* v = (const float*)d_in[2];
  const int* mask = (const int*)d_in[3];
  float* out = (float*)d_out;
  float* score = out + OUT_ELEMS;

  dim3 grid(L_ / 64, H_, B_);
  attn_kernel<<<grid, 256, 0, stream>>>(q, k, v, mask, out, score);
}

// Round 3
// 335.892 us; speedup vs baseline: 2.3538x; 2.3538x over previous
//
#include <hip/hip_runtime.h>
#include <math.h>

#define B_ 2
#define H_ 16
#define L_ 2048
#define D_ 64
#define SCALE 0.125f
#define NCH (L_ / 64)
#define OUT_ELEMS ((size_t)B_ * H_ * L_ * D_)
#define PITCH 72

typedef _Float16 half8 __attribute__((ext_vector_type(8)));
typedef _Float16 half4_t __attribute__((ext_vector_type(4)));
typedef float f32x4 __attribute__((ext_vector_type(4)));
typedef int i32x4 __attribute__((ext_vector_type(4)));

// Block = 256 threads = 4 waves; block owns (b, h, 64 q-rows); wave owns 16.
// Swapped QK^T: acc[kb4][r] = S[k = kc+kb4*16+lg*4+r][q = q0+wv*16+lr].
// Lane-local stats per q-row (lr), replicated across the 4 lg groups.
__global__ __launch_bounds__(256, 4) void attn_kernel(
    const float* __restrict__ Q, const float* __restrict__ K,
    const float* __restrict__ V, const int* __restrict__ M,
    float* __restrict__ out, float* __restrict__ score)
{
  const int qt = blockIdx.x, h = blockIdx.y, b = blockIdx.z;
  const int bh = b * H_ + h;
  const int q0 = qt * 64;
  const int tid = threadIdx.x;
  const int wv = tid >> 6, lane = tid & 63;
  const int lr = lane & 15, lg = lane >> 4;
  const int qrow = q0 + wv * 16 + lr;

  __shared__ _Float16 Klds[2][64][PITCH];   // K chunk [k][d], double-buffered
  __shared__ _Float16 Vtlds[64][PITCH];     // V chunk transposed [d][k]
  __shared__ _Float16 Plds[4][16][PITCH];   // per-wave P [q16][k]

  const float* kbase = K + (size_t)bh * L_ * D_;
  const float* vbase = V + (size_t)bh * L_ * D_;
  const int* mrow = M + (size_t)b * L_ * L_ + (size_t)qrow * L_;
  float* srow = score + ((size_t)bh * L_ + qrow) * L_;
  float* ob = out + (size_t)(bh * L_ + q0) * D_;

  // ---- Q fragment (B-operand): lane holds Q[qrow][d = f*32 + lg*8 + j] ----
  half8 qf[2];
  {
    const float* qr = Q + (size_t)(bh * L_ + qrow) * D_;
#pragma unroll
    for (int f = 0; f < 2; ++f) {
      f32x4 x = *(const f32x4*)(qr + f * 32 + lg * 8);
      f32x4 y = *(const f32x4*)(qr + f * 32 + lg * 8 + 4);
      qf[f] = half8{(_Float16)x[0], (_Float16)x[1], (_Float16)x[2], (_Float16)x[3],
                    (_Float16)y[0], (_Float16)y[1], (_Float16)y[2], (_Float16)y[3]};
    }
  }

  const int ksr = tid >> 2, ksd = (tid & 3) * 16;   // K staging: row, 16-d slice
  const int vk0 = (tid >> 4) * 4, vd0 = (tid & 15) * 4; // V staging: 4k x 4d block

  auto loadK4 = [&](int kc, f32x4* r) {
    const float* s = kbase + (size_t)(kc + ksr) * D_ + ksd;
    r[0] = ((const f32x4*)s)[0]; r[1] = ((const f32x4*)s)[1];
    r[2] = ((const f32x4*)s)[2]; r[3] = ((const f32x4*)s)[3];
  };
  auto writeK = [&](int buf, const f32x4* r) {
    half8 lo = half8{(_Float16)r[0][0], (_Float16)r[0][1], (_Float16)r[0][2], (_Float16)r[0][3],
                     (_Float16)r[1][0], (_Float16)r[1][1], (_Float16)r[1][2], (_Float16)r[1][3]};
    half8 hi = half8{(_Float16)r[2][0], (_Float16)r[2][1], (_Float16)r[2][2], (_Float16)r[2][3],
                     (_Float16)r[3][0], (_Float16)r[3][1], (_Float16)r[3][2], (_Float16)r[3][3]};
    *(half8*)&Klds[buf][ksr][ksd] = lo;
    *(half8*)&Klds[buf][ksr][ksd + 8] = hi;
  };
  auto loadV4 = [&](int kc, f32x4* r) {
#pragma unroll
    for (int i = 0; i < 4; ++i)
      r[i] = *(const f32x4*)(vbase + (size_t)(kc + vk0 + i) * D_ + vd0);
  };
  auto writeV = [&](const f32x4* r) {
#pragma unroll
    for (int j = 0; j < 4; ++j) {
      *(half4_t*)&Vtlds[vd0 + j][vk0] =
          half4_t{(_Float16)r[0][j], (_Float16)r[1][j],
                  (_Float16)r[2][j], (_Float16)r[3][j]};
    }
  };

  float m_r = -INFINITY, l_r = 0.f;

  // ======================= pass A: row stats =======================
  {
    f32x4 kr[4];
    loadK4(0, kr);
    writeK(0, kr);
  }
  __syncthreads();

  for (int c = 0; c < NCH; ++c) {
    const int kc = c * 64, cur = c & 1;
    f32x4 kr[4];
    if (c < NCH - 1) loadK4(kc + 64, kr);
    i32x4 mq[4];
#pragma unroll
    for (int kb = 0; kb < 4; ++kb)
      mq[kb] = *(const i32x4*)(mrow + kc + kb * 16 + lg * 4);

    f32x4 acc[4] = {f32x4{0,0,0,0}, f32x4{0,0,0,0}, f32x4{0,0,0,0}, f32x4{0,0,0,0}};
#pragma unroll
    for (int kb = 0; kb < 4; ++kb) {
      half8 a0 = *(const half8*)&Klds[cur][kb * 16 + lr][lg * 8];
      half8 a1 = *(const half8*)&Klds[cur][kb * 16 + lr][32 + lg * 8];
      acc[kb] = __builtin_amdgcn_mfma_f32_16x16x32_f16(a0, qf[0], acc[kb], 0, 0, 0);
      acc[kb] = __builtin_amdgcn_mfma_f32_16x16x32_f16(a1, qf[1], acc[kb], 0, 0, 0);
    }

    float cm = -INFINITY;
#pragma unroll
    for (int kb = 0; kb < 4; ++kb)
#pragma unroll
      for (int r = 0; r < 4; ++r) {
        float s = acc[kb][r] * SCALE;
        cm = fmaxf(cm, mq[kb][r] != 0 ? s : -INFINITY);
      }
    cm = fmaxf(cm, __shfl_xor(cm, 16));
    cm = fmaxf(cm, __shfl_xor(cm, 32));
    float mn = fmaxf(m_r, cm);
    float cs = 0.f;
#pragma unroll
    for (int kb = 0; kb < 4; ++kb)
#pragma unroll
      for (int r = 0; r < 4; ++r) {
        float s = acc[kb][r] * SCALE;
        cs += (mq[kb][r] != 0) ? __expf(s - mn) : 0.f;
      }
    cs += __shfl_xor(cs, 16);
    cs += __shfl_xor(cs, 32);
    l_r = l_r * ((m_r == mn) ? 1.f : __expf(m_r - mn)) + cs;
    m_r = mn;

    if (c < NCH - 1) writeK(cur ^ 1, kr);
    __syncthreads();
  }

  const float inv_l = (l_r > 0.f) ? 1.f / l_r : 0.f;
  const float m_use = (l_r > 0.f) ? m_r : 0.f;

  // ============ pass B: write P (score), accumulate O = P*V ============
  {
    f32x4 kr[4];
    loadK4(0, kr);
    writeK(0, kr);
  }
  __syncthreads();

  f32x4 o_acc[4] = {f32x4{0,0,0,0}, f32x4{0,0,0,0}, f32x4{0,0,0,0}, f32x4{0,0,0,0}};

  for (int c = 0; c < NCH; ++c) {
    const int kc = c * 64, cur = c & 1;
    f32x4 kr[4], vr[4];
    if (c < NCH - 1) loadK4(kc + 64, kr);
    loadV4(kc, vr);
    i32x4 mq[4];
#pragma unroll
    for (int kb = 0; kb < 4; ++kb)
      mq[kb] = *(const i32x4*)(mrow + kc + kb * 16 + lg * 4);

    f32x4 acc[4] = {f32x4{0,0,0,0}, f32x4{0,0,0,0}, f32x4{0,0,0,0}, f32x4{0,0,0,0}};
#pragma unroll
    for (int kb = 0; kb < 4; ++kb) {
      half8 a0 = *(const half8*)&Klds[cur][kb * 16 + lr][lg * 8];
      half8 a1 = *(const half8*)&Klds[cur][kb * 16 + lr][32 + lg * 8];
      acc[kb] = __builtin_amdgcn_mfma_f32_16x16x32_f16(a0, qf[0], acc[kb], 0, 0, 0);
      acc[kb] = __builtin_amdgcn_mfma_f32_16x16x32_f16(a1, qf[1], acc[kb], 0, 0, 0);
    }

#pragma unroll
    for (int kb = 0; kb < 4; ++kb) {
      f32x4 p4;
#pragma unroll
      for (int r = 0; r < 4; ++r) {
        float s = acc[kb][r] * SCALE;
        p4[r] = (mq[kb][r] != 0) ? __expf(s - m_use) * inv_l : 0.f;
      }
      *(f32x4*)(srow + kc + kb * 16 + lg * 4) = p4;
      *(half4_t*)&Plds[wv][lr][kb * 16 + lg * 4] =
          half4_t{(_Float16)p4[0], (_Float16)p4[1],
                  (_Float16)p4[2], (_Float16)p4[3]};
    }

    __syncthreads();          // prior iteration's PV readers of Vtlds are done
    writeV(vr);
    if (c < NCH - 1) writeK(cur ^ 1, kr);
    __syncthreads();          // V (and next K) ready

#pragma unroll
    for (int ks = 0; ks < 2; ++ks) {
      half8 pa = *(const half8*)&Plds[wv][lr][ks * 32 + lg * 8];
#pragma unroll
      for (int db = 0; db < 4; ++db) {
        half8 vf = *(const half8*)&Vtlds[db * 16 + lr][ks * 32 + lg * 8];
        o_acc[db] = __builtin_amdgcn_mfma_f32_16x16x32_f16(pa, vf, o_acc[db], 0, 0, 0);
      }
    }
  }

  // ---- write O: C row = q (lg*4+r), col = d (db*16+lr) ----
#pragma unroll
  for (int db = 0; db < 4; ++db)
#pragma unroll
    for (int r = 0; r < 4; ++r)
      ob[(size_t)(wv * 16 + lg * 4 + r) * D_ + db * 16 + lr] = o_acc[db][r];
}

extern "C" void kernel_launch(void* const* d_in, const int* in_sizes, int n_in,
                              void* d_out, int out_size, void* d_ws, size_t ws_size,
                              hipStream_t stream) {
  const float* q = (const float*)d_in[0];
  const float* k = (const float*)d_in[1];
  const float* v = (const float*)d_in[2];
  const int* mask = (const int*)d_in[3];
  float* out = (float*)d_out;
  float* score = out + OUT_ELEMS;

  dim3 grid(L_ / 64, H_, B_);
  attn_kernel<<<grid, 256, 0, stream>>>(q, k, v, mask, out, score);
}

// Round 5
// 284.346 us; speedup vs baseline: 2.7804x; 1.1813x over previous
//
#include <hip/hip_runtime.h>
#include <math.h>

#define B_ 2
#define H_ 16
#define L_ 2048
#define D_ 64
#define NCH (L_ / 64)
#define OUT_ELEMS ((size_t)B_ * H_ * L_ * D_)
#define PITCH 72
// SCALE * log2(e): scores computed directly in exp2 domain
#define C1 0.180336880f

typedef _Float16 half8 __attribute__((ext_vector_type(8)));
typedef _Float16 half4_t __attribute__((ext_vector_type(4)));
typedef float f32x4 __attribute__((ext_vector_type(4)));
typedef int i32x4 __attribute__((ext_vector_type(4)));

// Block = 256 threads = 4 waves; block owns (b, h, 64 q-rows); wave owns 16.
// Swapped QK^T: acc[kb][r] = S[k = kc+kb*16+lg*4+r][q = q0+wv*16+lr] (log2 units).
// Per-lane online (m,l); cross-lg merge once after pass A.
__global__ __launch_bounds__(256, 4) void attn_kernel(
    const float* __restrict__ Q, const float* __restrict__ K,
    const float* __restrict__ V, const int* __restrict__ M,
    float* __restrict__ out, float* __restrict__ score)
{
  const int qt = blockIdx.x, h = blockIdx.y, b = blockIdx.z;
  const int bh = b * H_ + h;
  const int q0 = qt * 64;
  const int tid = threadIdx.x;
  const int wv = tid >> 6, lane = tid & 63;
  const int lr = lane & 15, lg = lane >> 4;
  const int qrow = q0 + wv * 16 + lr;

  __shared__ _Float16 Klds[64][PITCH];     // K chunk [k][d] (pass A: K even-buf)
  __shared__ _Float16 Vlds[64][PITCH];     // V chunk [d][k] (pass A: K odd-buf)
  __shared__ _Float16 Plds[4][16][PITCH];  // per-wave P [q16][k]

  const float* kbase = K + (size_t)bh * L_ * D_;
  const float* vbase = V + (size_t)bh * L_ * D_;
  const int* mrow = M + (size_t)b * L_ * L_ + (size_t)qrow * L_;
  float* srow = score + ((size_t)bh * L_ + qrow) * L_;
  float* ob = out + (size_t)(bh * L_ + q0) * D_;

  // ---- Q fragment (B-operand), pre-scaled by SCALE*log2e ----
  half8 qf[2];
  {
    const float* qr = Q + (size_t)(bh * L_ + qrow) * D_;
#pragma unroll
    for (int f = 0; f < 2; ++f) {
      f32x4 x = *(const f32x4*)(qr + f * 32 + lg * 8);
      f32x4 y = *(const f32x4*)(qr + f * 32 + lg * 8 + 4);
      qf[f] = half8{(_Float16)(x[0]*C1), (_Float16)(x[1]*C1), (_Float16)(x[2]*C1), (_Float16)(x[3]*C1),
                    (_Float16)(y[0]*C1), (_Float16)(y[1]*C1), (_Float16)(y[2]*C1), (_Float16)(y[3]*C1)};
    }
  }

  const int ksr = tid >> 2, ksd = (tid & 3) * 16;     // K staging: row, 16-d slice
  const int vk0 = (tid & 15) * 4, vd0 = (tid >> 4) * 4; // V staging: 4k x 4d block

  auto loadK4 = [&](int kc, f32x4* r) {
    const float* s = kbase + (size_t)(kc + ksr) * D_ + ksd;
    r[0] = ((const f32x4*)s)[0]; r[1] = ((const f32x4*)s)[1];
    r[2] = ((const f32x4*)s)[2]; r[3] = ((const f32x4*)s)[3];
  };
  auto writeK = [&](_Float16 (*dst)[PITCH], const f32x4* r) {
    half8 lo = half8{(_Float16)r[0][0], (_Float16)r[0][1], (_Float16)r[0][2], (_Float16)r[0][3],
                     (_Float16)r[1][0], (_Float16)r[1][1], (_Float16)r[1][2], (_Float16)r[1][3]};
    half8 hi = half8{(_Float16)r[2][0], (_Float16)r[2][1], (_Float16)r[2][2], (_Float16)r[2][3],
                     (_Float16)r[3][0], (_Float16)r[3][1], (_Float16)r[3][2], (_Float16)r[3][3]};
    *(half8*)&dst[ksr][ksd] = lo;
    *(half8*)&dst[ksr][ksd + 8] = hi;
  };
  auto loadV4 = [&](int kc, f32x4* r) {
#pragma unroll
    for (int i = 0; i < 4; ++i)
      r[i] = *(const f32x4*)(vbase + (size_t)(kc + vk0 + i) * D_ + vd0);
  };
  auto writeV = [&](const f32x4* r) {
#pragma unroll
    for (int j = 0; j < 4; ++j) {
      *(half4_t*)&Vlds[vd0 + j][vk0] =
          half4_t{(_Float16)r[0][j], (_Float16)r[1][j],
                  (_Float16)r[2][j], (_Float16)r[3][j]};
    }
  };

  float m_l = -INFINITY, l_l = 0.f;

  // ======================= pass A: per-lane row stats =======================
  {
    f32x4 kr[4];
    loadK4(0, kr);
    writeK(Klds, kr);
  }
  __syncthreads();

  for (int c = 0; c < NCH; ++c) {
    const int kc = c * 64;
    _Float16 (*Kcur)[PITCH] = (c & 1) ? Vlds : Klds;
    _Float16 (*Knx)[PITCH]  = (c & 1) ? Klds : Vlds;

    f32x4 kr[4];
    if (c < NCH - 1) loadK4(kc + 64, kr);
    i32x4 mq[4];
#pragma unroll
    for (int kb = 0; kb < 4; ++kb)
      mq[kb] = *(const i32x4*)(mrow + kc + kb * 16 + lg * 4);

    f32x4 acc[4] = {f32x4{0,0,0,0}, f32x4{0,0,0,0}, f32x4{0,0,0,0}, f32x4{0,0,0,0}};
    __builtin_amdgcn_s_setprio(1);
#pragma unroll
    for (int kb = 0; kb < 4; ++kb) {
      half8 a0 = *(const half8*)&Kcur[kb * 16 + lr][lg * 8];
      half8 a1 = *(const half8*)&Kcur[kb * 16 + lr][32 + lg * 8];
      acc[kb] = __builtin_amdgcn_mfma_f32_16x16x32_f16(a0, qf[0], acc[kb], 0, 0, 0);
      acc[kb] = __builtin_amdgcn_mfma_f32_16x16x32_f16(a1, qf[1], acc[kb], 0, 0, 0);
    }
    __builtin_amdgcn_s_setprio(0);

    // unmasked running max (log2 units); masked exp2-sum
    float cm = m_l;
#pragma unroll
    for (int kb = 0; kb < 4; ++kb)
#pragma unroll
      for (int r = 0; r < 4; ++r)
        cm = fmaxf(cm, acc[kb][r]);
    float cs = 0.f;
#pragma unroll
    for (int kb = 0; kb < 4; ++kb)
#pragma unroll
      for (int r = 0; r < 4; ++r) {
        float t = acc[kb][r] - cm;
        cs += exp2f(mq[kb][r] != 0 ? t : -INFINITY);
      }
    l_l = l_l * exp2f(m_l - cm) + cs;
    m_l = cm;

    if (c < NCH - 1) writeK(Knx, kr);
    __syncthreads();
  }

  // cross-lg merge (lanes differing in bits 4,5 share a q-row)
  float mg = fmaxf(m_l, __shfl_xor(m_l, 16));
  mg = fmaxf(mg, __shfl_xor(mg, 32));
  float lc = l_l * exp2f(m_l - mg);
  lc += __shfl_xor(lc, 16);
  lc += __shfl_xor(lc, 32);
  const float inv_l = (lc > 0.f) ? 1.f / lc : 0.f;
  const float m_use = mg;

  // ============ pass B: write P (score, NT), accumulate O = P*V ============
  {
    f32x4 kr[4], vr[4];
    loadK4(0, kr);
    loadV4(0, vr);
    writeK(Klds, kr);
    writeV(vr);
  }
  __syncthreads();

  f32x4 o_acc[4] = {f32x4{0,0,0,0}, f32x4{0,0,0,0}, f32x4{0,0,0,0}, f32x4{0,0,0,0}};
  f32x4 krP[4], vrP[4];

  for (int c = 0; c < NCH; ++c) {
    const int kc = c * 64;
    if (c > 0) {
      __syncthreads();            // everyone done reading K/V of chunk c-1
      writeK(Klds, krP);
      writeV(vrP);
      __syncthreads();            // chunk c staged
    }
    // prefetch next chunk into registers (consumed at next iter's top)
    if (c < NCH - 1) {
      loadK4(kc + 64, krP);
      loadV4(kc + 64, vrP);
    }
    i32x4 mq[4];
#pragma unroll
    for (int kb = 0; kb < 4; ++kb)
      mq[kb] = *(const i32x4*)(mrow + kc + kb * 16 + lg * 4);

    f32x4 acc[4] = {f32x4{0,0,0,0}, f32x4{0,0,0,0}, f32x4{0,0,0,0}, f32x4{0,0,0,0}};
    __builtin_amdgcn_s_setprio(1);
#pragma unroll
    for (int kb = 0; kb < 4; ++kb) {
      half8 a0 = *(const half8*)&Klds[kb * 16 + lr][lg * 8];
      half8 a1 = *(const half8*)&Klds[kb * 16 + lr][32 + lg * 8];
      acc[kb] = __builtin_amdgcn_mfma_f32_16x16x32_f16(a0, qf[0], acc[kb], 0, 0, 0);
      acc[kb] = __builtin_amdgcn_mfma_f32_16x16x32_f16(a1, qf[1], acc[kb], 0, 0, 0);
    }
    __builtin_amdgcn_s_setprio(0);

#pragma unroll
    for (int kb = 0; kb < 4; ++kb) {
      f32x4 p4;
#pragma unroll
      for (int r = 0; r < 4; ++r) {
        float t = acc[kb][r] - m_use;
        p4[r] = exp2f(mq[kb][r] != 0 ? t : -INFINITY) * inv_l;
      }
      __builtin_nontemporal_store(p4, (f32x4*)(srow + kc + kb * 16 + lg * 4));
      *(half4_t*)&Plds[wv][lr][kb * 16 + lg * 4] =
          half4_t{(_Float16)p4[0], (_Float16)p4[1],
                  (_Float16)p4[2], (_Float16)p4[3]};
    }

    __builtin_amdgcn_s_setprio(1);
#pragma unroll
    for (int ks = 0; ks < 2; ++ks) {
      half8 pa = *(const half8*)&Plds[wv][lr][ks * 32 + lg * 8];
#pragma unroll
      for (int db = 0; db < 4; ++db) {
        half8 vf = *(const half8*)&Vlds[db * 16 + lr][ks * 32 + lg * 8];
        o_acc[db] = __builtin_amdgcn_mfma_f32_16x16x32_f16(pa, vf, o_acc[db], 0, 0, 0);
      }
    }
    __builtin_amdgcn_s_setprio(0);
  }

  // ---- write O (NT): row = q (wv*16+lg*4+r), col = d (db*16+lr) ----
#pragma unroll
  for (int db = 0; db < 4; ++db)
#pragma unroll
    for (int r = 0; r < 4; ++r)
      __builtin_nontemporal_store(
          o_acc[db][r], ob + (size_t)(wv * 16 + lg * 4 + r) * D_ + db * 16 + lr);
}

extern "C" void kernel_launch(void* const* d_in, const int* in_sizes, int n_in,
                              void* d_out, int out_size, void* d_ws, size_t ws_size,
                              hipStream_t stream) {
  const float* q = (const float*)d_in[0];
  const float* k = (const float*)d_in[1];
  const float* v = (const float*)d_in[2];
  const int* mask = (const int*)d_in[3];
  float* out = (float*)d_out;
  float* score = out + OUT_ELEMS;

  dim3 grid(L_ / 64, H_, B_);
  attn_kernel<<<grid, 256, 0, stream>>>(q, k, v, mask, out, score);
}

// Round 6
// 255.080 us; speedup vs baseline: 3.0994x; 1.1147x over previous
//
#include <hip/hip_runtime.h>
#include <math.h>

#define B_ 2
#define H_ 16
#define L_ 2048
#define D_ 64
#define NCH (L_ / 64)
#define NWG (B_ * H_ * (L_ / 64))   // 1024
#define OUT_ELEMS ((size_t)B_ * H_ * L_ * D_)
#define PITCH 72
// SCALE * log2(e): scores computed directly in exp2 domain
#define C1 0.180336880f

typedef _Float16 half8 __attribute__((ext_vector_type(8)));
typedef _Float16 half4_t __attribute__((ext_vector_type(4)));
typedef float f32x4 __attribute__((ext_vector_type(4)));
typedef int i32x4 __attribute__((ext_vector_type(4)));
typedef unsigned int u32;
typedef u32 u32x4 __attribute__((ext_vector_type(4)));
typedef u32 u32x2 __attribute__((ext_vector_type(2)));

// Block = 256 threads = 4 waves; block owns (b, h, 64 q-rows); wave owns 16.
// Swapped QK^T: acc[kb][r] = S[k = kc+kb*16+lg*4+r][q = q0+wv*16+lr] (log2 units).
// Mask bits packed once (pass A) into LDS; P redistributed for PV via shuffles.
__global__ __launch_bounds__(256, 4) void attn_kernel(
    const float* __restrict__ Q, const float* __restrict__ K,
    const float* __restrict__ V, const int* __restrict__ M,
    float* __restrict__ out, float* __restrict__ score)
{
  // XCD-aware swizzle: XCD x gets contiguous logical ids [x*128, x*128+128).
  // Logical decode qt-fastest => resident blocks on an XCD share few bh (K/V in L2).
  const int bid = blockIdx.x;
  const int lid = (bid & 7) * (NWG / 8) + (bid >> 3);
  const int qt = lid & 31, h = (lid >> 5) & 15, b = lid >> 9;

  const int bh = b * H_ + h;
  const int q0 = qt * 64;
  const int tid = threadIdx.x;
  const int wv = tid >> 6, lane = tid & 63;
  const int lr = lane & 15, lg = lane >> 4;
  const int qrow = q0 + wv * 16 + lr;

  __shared__ _Float16 Klds[64][PITCH];       // K chunk [k][d] (pass A: even buf)
  __shared__ _Float16 Vlds[64][PITCH];       // V chunk [d][k] (pass A: odd buf)
  __shared__ unsigned short mb16[NCH][256];  // per-lane 16 mask bits per chunk

  const float* kbase = K + (size_t)bh * L_ * D_;
  const float* vbase = V + (size_t)bh * L_ * D_;
  const int* mrow = M + (size_t)b * L_ * L_ + (size_t)qrow * L_;
  float* srow = score + ((size_t)bh * L_ + qrow) * L_;
  float* ob = out + (size_t)(bh * L_ + q0) * D_;

  // ---- Q fragment (B-operand), pre-scaled by SCALE*log2e ----
  half8 qf[2];
  {
    const float* qr = Q + (size_t)(bh * L_ + qrow) * D_;
#pragma unroll
    for (int f = 0; f < 2; ++f) {
      f32x4 x = *(const f32x4*)(qr + f * 32 + lg * 8);
      f32x4 y = *(const f32x4*)(qr + f * 32 + lg * 8 + 4);
      qf[f] = half8{(_Float16)(x[0]*C1), (_Float16)(x[1]*C1), (_Float16)(x[2]*C1), (_Float16)(x[3]*C1),
                    (_Float16)(y[0]*C1), (_Float16)(y[1]*C1), (_Float16)(y[2]*C1), (_Float16)(y[3]*C1)};
    }
  }

  const int ksr = tid >> 2, ksd = (tid & 3) * 16;       // K staging: row, 16-d slice
  const int vk0 = (tid & 15) * 4, vd0 = (tid >> 4) * 4; // V staging: 4k x 4d block

  auto loadK4 = [&](int kc, f32x4* r) {
    const float* s = kbase + (size_t)(kc + ksr) * D_ + ksd;
    r[0] = ((const f32x4*)s)[0]; r[1] = ((const f32x4*)s)[1];
    r[2] = ((const f32x4*)s)[2]; r[3] = ((const f32x4*)s)[3];
  };
  auto writeK = [&](_Float16 (*dst)[PITCH], const f32x4* r) {
    half8 lo = half8{(_Float16)r[0][0], (_Float16)r[0][1], (_Float16)r[0][2], (_Float16)r[0][3],
                     (_Float16)r[1][0], (_Float16)r[1][1], (_Float16)r[1][2], (_Float16)r[1][3]};
    half8 hi = half8{(_Float16)r[2][0], (_Float16)r[2][1], (_Float16)r[2][2], (_Float16)r[2][3],
                     (_Float16)r[3][0], (_Float16)r[3][1], (_Float16)r[3][2], (_Float16)r[3][3]};
    *(half8*)&dst[ksr][ksd] = lo;
    *(half8*)&dst[ksr][ksd + 8] = hi;
  };
  auto loadV4 = [&](int kc, f32x4* r) {
#pragma unroll
    for (int i = 0; i < 4; ++i)
      r[i] = *(const f32x4*)(vbase + (size_t)(kc + vk0 + i) * D_ + vd0);
  };
  auto writeV = [&](const f32x4* r) {
#pragma unroll
    for (int j = 0; j < 4; ++j) {
      *(half4_t*)&Vlds[vd0 + j][vk0] =
          half4_t{(_Float16)r[0][j], (_Float16)r[1][j],
                  (_Float16)r[2][j], (_Float16)r[3][j]};
    }
  };

  float m_l = -INFINITY, l_l = 0.f;

  // ======================= pass A: per-lane row stats =======================
  {
    f32x4 kr[4];
    loadK4(0, kr);
    writeK(Klds, kr);
  }
  __syncthreads();

  for (int c = 0; c < NCH; ++c) {
    const int kc = c * 64;
    _Float16 (*Kcur)[PITCH] = (c & 1) ? Vlds : Klds;
    _Float16 (*Knx)[PITCH]  = (c & 1) ? Klds : Vlds;

    f32x4 kr[4];
    if (c < NCH - 1) loadK4(kc + 64, kr);
    i32x4 mq[4];
#pragma unroll
    for (int kb = 0; kb < 4; ++kb)
      mq[kb] = *(const i32x4*)(mrow + kc + kb * 16 + lg * 4);

    f32x4 acc[4] = {f32x4{0,0,0,0}, f32x4{0,0,0,0}, f32x4{0,0,0,0}, f32x4{0,0,0,0}};
    __builtin_amdgcn_s_setprio(1);
#pragma unroll
    for (int kb = 0; kb < 4; ++kb) {
      half8 a0 = *(const half8*)&Kcur[kb * 16 + lr][lg * 8];
      half8 a1 = *(const half8*)&Kcur[kb * 16 + lr][32 + lg * 8];
      acc[kb] = __builtin_amdgcn_mfma_f32_16x16x32_f16(a0, qf[0], acc[kb], 0, 0, 0);
      acc[kb] = __builtin_amdgcn_mfma_f32_16x16x32_f16(a1, qf[1], acc[kb], 0, 0, 0);
    }
    __builtin_amdgcn_s_setprio(0);

    // pack mask bits for pass B
    u32 bits = 0;
#pragma unroll
    for (int kb = 0; kb < 4; ++kb)
#pragma unroll
      for (int r = 0; r < 4; ++r)
        bits |= (mq[kb][r] != 0 ? 1u : 0u) << (kb * 4 + r);
    mb16[c][tid] = (unsigned short)bits;

    // unmasked running max (log2 units); masked exp2-sum
    float cm = m_l;
#pragma unroll
    for (int kb = 0; kb < 4; ++kb)
#pragma unroll
      for (int r = 0; r < 4; ++r)
        cm = fmaxf(cm, acc[kb][r]);
    float cs = 0.f;
#pragma unroll
    for (int kb = 0; kb < 4; ++kb)
#pragma unroll
      for (int r = 0; r < 4; ++r) {
        float t = acc[kb][r] - cm;
        cs += exp2f(mq[kb][r] != 0 ? t : -INFINITY);
      }
    l_l = l_l * exp2f(m_l - cm) + cs;
    m_l = cm;

    if (c < NCH - 1) writeK(Knx, kr);
    __syncthreads();
  }

  // cross-lg merge (lanes differing in bits 4,5 share a q-row)
  float mg = fmaxf(m_l, __shfl_xor(m_l, 16));
  mg = fmaxf(mg, __shfl_xor(mg, 32));
  float lc = l_l * exp2f(m_l - mg);
  lc += __shfl_xor(lc, 16);
  lc += __shfl_xor(lc, 32);
  const float inv_l = (lc > 0.f) ? 1.f / lc : 0.f;
  const float m_use = mg;

  // ============ pass B: write P (score, NT), accumulate O = P*V ============
  {
    f32x4 kr[4], vr[4];
    loadK4(0, kr);
    loadV4(0, vr);
    writeK(Klds, kr);
    writeV(vr);
  }
  __syncthreads();

  f32x4 o_acc[4] = {f32x4{0,0,0,0}, f32x4{0,0,0,0}, f32x4{0,0,0,0}, f32x4{0,0,0,0}};
  f32x4 krP[4], vrP[4];

  const int s0lane = lr + 32 * (lg & 1);   // P-shuffle sources
  const int s1lane = s0lane + 16;
  const bool hisel = (lg & 2) != 0;

  for (int c = 0; c < NCH; ++c) {
    const int kc = c * 64;
    if (c > 0) {
      __syncthreads();            // everyone done reading K/V of chunk c-1
      writeK(Klds, krP);
      writeV(vrP);
      __syncthreads();            // chunk c staged
    }
    // prefetch next chunk into registers (consumed at next iter's top)
    if (c < NCH - 1) {
      loadK4(kc + 64, krP);
      loadV4(kc + 64, vrP);
    }
    const u32 w = mb16[c][tid];

    f32x4 acc[4] = {f32x4{0,0,0,0}, f32x4{0,0,0,0}, f32x4{0,0,0,0}, f32x4{0,0,0,0}};
    __builtin_amdgcn_s_setprio(1);
#pragma unroll
    for (int kb = 0; kb < 4; ++kb) {
      half8 a0 = *(const half8*)&Klds[kb * 16 + lr][lg * 8];
      half8 a1 = *(const half8*)&Klds[kb * 16 + lr][32 + lg * 8];
      acc[kb] = __builtin_amdgcn_mfma_f32_16x16x32_f16(a0, qf[0], acc[kb], 0, 0, 0);
      acc[kb] = __builtin_amdgcn_mfma_f32_16x16x32_f16(a1, qf[1], acc[kb], 0, 0, 0);
    }
    __builtin_amdgcn_s_setprio(0);

    // P = exp2(S - m)/l ; NT-store to score; pack halves for shuffle
    u32 phu[8];
#pragma unroll
    for (int kb = 0; kb < 4; ++kb) {
      f32x4 p4;
#pragma unroll
      for (int r = 0; r < 4; ++r) {
        float t = acc[kb][r] - m_use;
        p4[r] = exp2f(((w >> (kb * 4 + r)) & 1u) ? t : -INFINITY) * inv_l;
      }
      __builtin_nontemporal_store(p4, (f32x4*)(srow + kc + kb * 16 + lg * 4));
      half4_t hp = half4_t{(_Float16)p4[0], (_Float16)p4[1],
                           (_Float16)p4[2], (_Float16)p4[3]};
      u32x2 uu = __builtin_bit_cast(u32x2, hp);
      phu[2 * kb] = uu[0];
      phu[2 * kb + 1] = uu[1];
    }

    // Redistribute P: lane(lr,lg) gathers P[q=lr][k=ks*32+lg*8+j] from
    // lanes s0lane (j=0..3) and s1lane (j=4..7), kb-half chosen by lg&2.
    __builtin_amdgcn_s_setprio(1);
#pragma unroll
    for (int ks = 0; ks < 2; ++ks) {
      int a0 = __shfl((int)phu[4 * ks + 0], s0lane);
      int a1 = __shfl((int)phu[4 * ks + 1], s0lane);
      int a2 = __shfl((int)phu[4 * ks + 2], s0lane);
      int a3 = __shfl((int)phu[4 * ks + 3], s0lane);
      int b0 = __shfl((int)phu[4 * ks + 0], s1lane);
      int b1 = __shfl((int)phu[4 * ks + 1], s1lane);
      int b2 = __shfl((int)phu[4 * ks + 2], s1lane);
      int b3 = __shfl((int)phu[4 * ks + 3], s1lane);
      u32x4 pau = u32x4{(u32)(hisel ? a2 : a0), (u32)(hisel ? a3 : a1),
                        (u32)(hisel ? b2 : b0), (u32)(hisel ? b3 : b1)};
      half8 pa = __builtin_bit_cast(half8, pau);
#pragma unroll
      for (int db = 0; db < 4; ++db) {
        half8 vf = *(const half8*)&Vlds[db * 16 + lr][ks * 32 + lg * 8];
        o_acc[db] = __builtin_amdgcn_mfma_f32_16x16x32_f16(pa, vf, o_acc[db], 0, 0, 0);
      }
    }
    __builtin_amdgcn_s_setprio(0);
  }

  // ---- write O (NT): row = q (wv*16+lg*4+r), col = d (db*16+lr) ----
#pragma unroll
  for (int db = 0; db < 4; ++db)
#pragma unroll
    for (int r = 0; r < 4; ++r)
      __builtin_nontemporal_store(
          o_acc[db][r], ob + (size_t)(wv * 16 + lg * 4 + r) * D_ + db * 16 + lr);
}

extern "C" void kernel_launch(void* const* d_in, const int* in_sizes, int n_in,
                              void* d_out, int out_size, void* d_ws, size_t ws_size,
                              hipStream_t stream) {
  const float* q = (const float*)d_in[0];
  const float* k = (const float*)d_in[1];
  const float* v = (const float*)d_in[2];
  const int* mask = (const int*)d_in[3];
  float* out = (float*)d_out;
  float* score = out + OUT_ELEMS;

  attn_kernel<<<dim3(NWG), 256, 0, stream>>>(q, k, v, mask, out, score);
}